// Round 2
// baseline (2831.518 us; speedup 1.0000x reference)
//
#include <hip/hip_runtime.h>
#include <hip/hip_bf16.h>
#include <math.h>

using bf16 = __hip_bfloat16;

#define BATCH 4
#define SEQL 2048
#define TOK (BATCH * SEQL)     // 8192
#define DMODEL 128
#define DINNER 256
#define NSTATE 16
#define NCHUNK 32
#define TCHUNK 64              // 32*64 = 2048

#define NPAR 28
#define PAR_TOTAL 3227264

struct Srcs { const void* p[NPAR]; int off[NPAR + 1]; };

// ---------------------------------------------------------------------------
// Decide whether inputs are bf16 (flag=1) or fp32 (flag=0) by exponent sanity
// of both 16-bit halves of the first 128 words of x (x ~ N(0,1)).
__global__ __launch_bounds__(128) void sniff_kernel(const unsigned int* __restrict__ xw,
                                                    int* __restrict__ flag) {
    __shared__ int cnt;
    if (threadIdx.x == 0) cnt = 0;
    __syncthreads();
    unsigned u = xw[threadIdx.x];
    unsigned elo = (u >> 7) & 0xFF;          // exponent if low half is bf16
    unsigned ehi = (u >> 23) & 0xFF;         // exponent of high half / fp32
    int ok = (elo >= 100 && elo <= 140) && (ehi >= 100 && ehi <= 140);
    if (ok) atomicAdd(&cnt, 1);
    __syncthreads();
    if (threadIdx.x == 0) *flag = (cnt >= 96) ? 1 : 0;
}

// Convert all 28 tensors into one fp32 parameter block.
__global__ __launch_bounds__(256) void cvt_all(Srcs s, const int* __restrict__ flag,
                                               float* __restrict__ dst, int total) {
    int idx = blockIdx.x * 256 + threadIdx.x;
    if (idx >= total) return;
    int t = 0;
    while (idx >= s.off[t + 1]) ++t;
    int j = idx - s.off[t];
    float v;
    if (*flag) v = __bfloat162float(((const bf16*)s.p[t])[j]);
    else       v = ((const float*)s.p[t])[j];
    dst[idx] = v;
}

// ---------------------------------------------------------------------------
// C[m,n] = act( A[m,:K] . W[n,:K] + bias[n] ) + res[m,n]
// A fp32 (lda), W fp32 (N,K) row-major, bias fp32 or null, res fp32 or null
// act: 0 none, 1 relu, 2 softplus
__global__ __launch_bounds__(256) void gemm_bias(const float* __restrict__ A,
                                                 const float* __restrict__ W,
                                                 const float* __restrict__ bias,
                                                 const float* __restrict__ res,
                                                 float* __restrict__ C,
                                                 int M, int N, int K, int lda, int act) {
    __shared__ float As[16][65];
    __shared__ float Bs[16][65];
    const int bm = blockIdx.y * 64, bn = blockIdx.x * 64;
    const int tid = threadIdx.x;
    const int tr = (tid >> 4) * 4;
    const int tc = (tid & 15) * 4;
    float acc[4][4] = {};
    for (int k0 = 0; k0 < K; k0 += 16) {
        #pragma unroll
        for (int i = 0; i < 4; ++i) {
            int e = tid * 4 + i; int r = e >> 4, kk = e & 15;
            float v = 0.f;
            if (k0 + kk < K) v = A[(size_t)(bm + r) * lda + k0 + kk];
            As[kk][r] = v;
        }
        #pragma unroll
        for (int i = 0; i < 4; ++i) {
            int e = tid * 4 + i; int n = e >> 4, kk = e & 15;
            float v = 0.f;
            if (bn + n < N && k0 + kk < K)
                v = W[(size_t)(bn + n) * K + k0 + kk];
            Bs[kk][n] = v;
        }
        __syncthreads();
        #pragma unroll
        for (int kk = 0; kk < 16; ++kk) {
            float a[4], b[4];
            #pragma unroll
            for (int i = 0; i < 4; ++i) a[i] = As[kk][tr + i];
            #pragma unroll
            for (int j = 0; j < 4; ++j) b[j] = Bs[kk][tc + j];
            #pragma unroll
            for (int i = 0; i < 4; ++i)
                #pragma unroll
                for (int j = 0; j < 4; ++j) acc[i][j] += a[i] * b[j];
        }
        __syncthreads();
    }
    #pragma unroll
    for (int i = 0; i < 4; ++i) {
        int m = bm + tr + i;
        #pragma unroll
        for (int j = 0; j < 4; ++j) {
            int n = bn + tc + j;
            if (n < N) {
                float v = acc[i][j];
                if (bias) v += bias[n];
                if (act == 1) v = fmaxf(v, 0.f);
                else if (act == 2) v = (v > 20.f) ? v : log1pf(__expf(v));
                if (res) v += res[(size_t)m * N + n];
                C[(size_t)m * N + n] = v;
            }
        }
    }
}

// ---------------------------------------------------------------------------
// LayerNorm over last dim (128). One wave per row, 4 rows per block.
// If outf: write fp32. Else write to outd as bf16 (*flag) or fp32.
__global__ __launch_bounds__(256) void ln_kernel(const float* __restrict__ in,
                                                 const float* __restrict__ s,
                                                 const float* __restrict__ bta,
                                                 float* __restrict__ outf,
                                                 void* __restrict__ outd,
                                                 const int* __restrict__ flag) {
    int wave = threadIdx.x >> 6, lane = threadIdx.x & 63;
    size_t row = (size_t)blockIdx.x * 4 + wave;
    const float* x = in + row * 128;
    float v0 = x[lane], v1 = x[lane + 64];
    float sum = v0 + v1;
    #pragma unroll
    for (int off = 32; off; off >>= 1) sum += __shfl_xor(sum, off);
    float mu = sum * (1.f / 128.f);
    float d0 = v0 - mu, d1 = v1 - mu;
    float vs = d0 * d0 + d1 * d1;
    #pragma unroll
    for (int off = 32; off; off >>= 1) vs += __shfl_xor(vs, off);
    float rstd = rsqrtf(vs * (1.f / 128.f) + 1e-5f);
    float y0 = d0 * rstd * s[lane] + bta[lane];
    float y1 = d1 * rstd * s[lane + 64] + bta[lane + 64];
    if (outf) {
        outf[row * 128 + lane] = y0; outf[row * 128 + lane + 64] = y1;
    } else if (*flag) {
        ((bf16*)outd)[row * 128 + lane] = __float2bfloat16(y0);
        ((bf16*)outd)[row * 128 + lane + 64] = __float2bfloat16(y1);
    } else {
        ((float*)outd)[row * 128 + lane] = y0;
        ((float*)outd)[row * 128 + lane + 64] = y1;
    }
}

// ---------------------------------------------------------------------------
// Flash attention, no mask. qkv (TOK, 384) fp32; out (TOK, 128) fp32.
__global__ __launch_bounds__(128) void attn_kernel(const float* __restrict__ qkv,
                                                   float* __restrict__ out) {
    __shared__ float Q[32][33], Kt[32][33], Vt[32][33], S[32][33];
    __shared__ float mrow[32], lrow[32], arow[32];
    const int bh = blockIdx.y; const int b = bh >> 2, hh = bh & 3;
    const int q0 = blockIdx.x * 32;
    const int tid = threadIdx.x;
    const int r4 = tid >> 2;
    const int c8 = (tid & 3) * 8;
    const size_t base = (size_t)b * SEQL * 384 + (size_t)hh * 32;
    #pragma unroll
    for (int j = 0; j < 8; ++j)
        Q[r4][c8 + j] = qkv[base + (size_t)(q0 + r4) * 384 + c8 + j];
    float o[8] = {};
    if (tid < 32) { mrow[tid] = -1e30f; lrow[tid] = 0.f; }
    __syncthreads();
    for (int kt = 0; kt < SEQL; kt += 32) {
        #pragma unroll
        for (int j = 0; j < 8; ++j) {
            Kt[r4][c8 + j] = qkv[base + (size_t)(kt + r4) * 384 + 128 + c8 + j];
            Vt[r4][c8 + j] = qkv[base + (size_t)(kt + r4) * 384 + 256 + c8 + j];
        }
        __syncthreads();
        #pragma unroll
        for (int j = 0; j < 8; ++j) {
            float sv = 0.f;
            #pragma unroll
            for (int k = 0; k < 32; ++k) sv += Q[r4][k] * Kt[c8 + j][k];
            S[r4][c8 + j] = sv * 0.17677669529663687f;
        }
        __syncthreads();
        if (tid < 32) {
            float m = mrow[tid], mn = m;
            for (int k = 0; k < 32; ++k) mn = fmaxf(mn, S[tid][k]);
            float alpha = __expf(m - mn);
            float lsum = 0.f;
            for (int k = 0; k < 32; ++k) {
                float pp = __expf(S[tid][k] - mn);
                S[tid][k] = pp; lsum += pp;
            }
            lrow[tid] = lrow[tid] * alpha + lsum;
            mrow[tid] = mn; arow[tid] = alpha;
        }
        __syncthreads();
        float alpha = arow[r4];
        #pragma unroll
        for (int j = 0; j < 8; ++j) {
            float accv = 0.f;
            #pragma unroll
            for (int k = 0; k < 32; ++k) accv += S[r4][k] * Vt[k][c8 + j];
            o[j] = o[j] * alpha + accv;
        }
        __syncthreads();
    }
    float linv = 1.f / lrow[r4];
    const size_t baseO = ((size_t)b * SEQL + q0 + r4) * 128 + (size_t)hh * 32;
    #pragma unroll
    for (int j = 0; j < 8; ++j) out[baseO + c8 + j] = o[j] * linv;
}

// ---------------------------------------------------------------------------
// causal depthwise conv (K=4) + silu. xz (TOK,512) fp32, x part cols [0,256).
__global__ __launch_bounds__(256) void conv_silu_kernel(const float* __restrict__ xz,
                                                        const float* __restrict__ w,
                                                        const float* __restrict__ cb,
                                                        float* __restrict__ out) {
    int idx = blockIdx.x * 256 + threadIdx.x;
    int d = idx & 255; int t = (idx >> 8) & (SEQL - 1); int b = idx >> 19;
    float acc = cb[d];
    #pragma unroll
    for (int k = 0; k < 4; ++k) {
        int tt = t - 3 + k;
        if (tt >= 0)
            acc += xz[((size_t)b * SEQL + tt) * 512 + d] * w[d * 4 + k];
    }
    out[idx] = acc / (1.f + __expf(-acc));
}

// ---------------------------------------------------------------------------
// SSM chunked scan.
__global__ __launch_bounds__(256) void scan_a(const float* __restrict__ dt,
                                              const float* __restrict__ xc,
                                              const float* __restrict__ dbc,
                                              const float* __restrict__ A_log,
                                              float* __restrict__ PS) {
    const int c = blockIdx.x & (NCHUNK - 1);
    const int dg = (blockIdx.x >> 5) & 15;
    const int b = blockIdx.x >> 9;
    const int dl = threadIdx.x >> 4, n = threadIdx.x & 15;
    const int d = dg * 16 + dl;
    const float Av = -__expf(A_log[d * 16 + n]);
    float P = 1.f, S = 0.f;
    const size_t tbase = (size_t)b * SEQL + c * TCHUNK;
    for (int t = 0; t < TCHUNK; ++t) {
        float dtv = dt[(tbase + t) * 256 + d];
        float xv = xc[(tbase + t) * 256 + d];
        float Bv = dbc[(tbase + t) * 40 + 8 + n];
        float a = __expf(dtv * Av);
        P *= a;
        S = a * S + dtv * xv * Bv;
    }
    size_t o = (((size_t)b * NCHUNK + c) * 256 + d) * 16 + n;
    PS[o] = S;
    PS[o + (size_t)BATCH * NCHUNK * 256 * 16] = P;
}

__global__ __launch_bounds__(256) void scan_b(const float* __restrict__ PS,
                                              float* __restrict__ H0) {
    int idx = blockIdx.x * 256 + threadIdx.x;   // BATCH*256*16 = 16384
    int n = idx & 15; int d = (idx >> 4) & 255; int b = idx >> 12;
    float h = 0.f;
    const size_t poff = (size_t)BATCH * NCHUNK * 256 * 16;
    for (int c = 0; c < NCHUNK; ++c) {
        size_t o = (((size_t)b * NCHUNK + c) * 256 + d) * 16 + n;
        H0[o] = h;
        h = PS[o + poff] * h + PS[o];
    }
}

__global__ __launch_bounds__(256) void scan_c(const float* __restrict__ dt,
                                              const float* __restrict__ xc,
                                              const float* __restrict__ dbc,
                                              const float* __restrict__ A_log,
                                              const float* __restrict__ H0,
                                              const float* __restrict__ xz,
                                              const float* __restrict__ Dp,
                                              float* __restrict__ y) {
    const int c = blockIdx.x & (NCHUNK - 1);
    const int dg = (blockIdx.x >> 5) & 15;
    const int b = blockIdx.x >> 9;
    const int dl = threadIdx.x >> 4, n = threadIdx.x & 15;
    const int d = dg * 16 + dl;
    const float Av = -__expf(A_log[d * 16 + n]);
    const float Dv = Dp[d];
    size_t o0 = (((size_t)b * NCHUNK + c) * 256 + d) * 16 + n;
    float h = H0[o0];
    const size_t tbase = (size_t)b * SEQL + c * TCHUNK;
    for (int t = 0; t < TCHUNK; ++t) {
        float dtv = dt[(tbase + t) * 256 + d];
        float xv = xc[(tbase + t) * 256 + d];
        float Bv = dbc[(tbase + t) * 40 + 8 + n];
        float Cv = dbc[(tbase + t) * 40 + 24 + n];
        float a = __expf(dtv * Av);
        h = a * h + dtv * xv * Bv;
        float p = h * Cv;
        p += __shfl_xor(p, 1); p += __shfl_xor(p, 2);
        p += __shfl_xor(p, 4); p += __shfl_xor(p, 8);
        if (n == 0) {
            float zv = xz[(tbase + t) * 512 + 256 + d];
            float sz = zv / (1.f + __expf(-zv));
            y[(tbase + t) * 256 + d] = (p + xv * Dv) * sz;
        }
    }
}

// ---------------------------------------------------------------------------
static inline void launch_gemm(const float* A, const float* W, const float* bias,
                               const float* res, float* C, int M, int N, int K,
                               int lda, int act, hipStream_t s) {
    dim3 g((N + 63) / 64, M / 64);
    hipLaunchKernelGGL(gemm_bias, g, dim3(256), 0, s, A, W, bias, res, C, M, N, K, lda, act);
}

static const int kSizes[NPAR] = {
    2097152, 32768, 128, 98304, 768, 32768, 256, 131072, 1024, 131072, 256,
    256, 256, 256, 256, 768, 768, 393216, 6144, 1536, 61440, 12288, 1536,
    24576, 1536, 196608, 128, 128
};

extern "C" void kernel_launch(void* const* d_in, const int* in_sizes, int n_in,
                              void* d_out, int out_size, void* d_ws, size_t ws_size,
                              hipStream_t stream) {
    Srcs srcs;
    int off[NPAR + 1];
    off[0] = 0;
    for (int i = 0; i < NPAR; ++i) {
        srcs.p[i] = d_in[i];
        off[i + 1] = off[i] + kSizes[i];
        srcs.off[i] = off[i];
    }
    srcs.off[NPAR] = off[NPAR];

    int* FLAG = (int*)d_ws;
    float* PAR = (float*)((char*)d_ws + 256);
    float* p = PAR + PAR_TOTAL;
    float* H   = p; p += (size_t)TOK * 128;
    float* XN  = p; p += (size_t)TOK * 128;
    float* T1  = p; p += (size_t)TOK * 512;
    float* T2  = p; p += (size_t)TOK * 256;
    float* T3  = p; p += (size_t)TOK * 128;
    float* DBC = p; p += (size_t)TOK * 40;
    float* DT  = p; p += (size_t)TOK * 256;
    float* Y   = p; p += (size_t)TOK * 256;
    float* PS  = p; p += (size_t)2 * BATCH * NCHUNK * 256 * 16;
    float* H0  = p; p += (size_t)BATCH * NCHUNK * 256 * 16;

    hipLaunchKernelGGL(sniff_kernel, dim3(1), dim3(128), 0, stream,
                       (const unsigned int*)d_in[0], FLAG);
    hipLaunchKernelGGL(cvt_all, dim3((PAR_TOTAL + 255) / 256), dim3(256), 0, stream,
                       srcs, FLAG, PAR, PAR_TOTAL);

    const float* Px        = PAR + off[0];
    const float* Pproj_w   = PAR + off[1];
    const float* Pproj_b   = PAR + off[2];
    const float* Pt_in_w   = PAR + off[3];
    const float* Pt_in_b   = PAR + off[4];
    const float* Pt_out_w  = PAR + off[5];
    const float* Pt_out_b  = PAR + off[6];
    const float* Pt_ff1_w  = PAR + off[7];
    const float* Pt_ff1_b  = PAR + off[8];
    const float* Pt_ff2_w  = PAR + off[9];
    const float* Pt_ff2_b  = PAR + off[10];
    const float* Pt_n1_s   = PAR + off[11];
    const float* Pt_n1_b   = PAR + off[12];
    const float* Pt_n2_s   = PAR + off[13];
    const float* Pt_n2_b   = PAR + off[14];
    const float* Pm_norm_s = PAR + off[15];
    const float* Pm_norm_b = PAR + off[16];
    const float* Pm_in_w   = PAR + off[17];
    const float* Pm_conv_w = PAR + off[18];
    const float* Pm_conv_b = PAR + off[19];
    const float* Pm_xproj_w= PAR + off[20];
    const float* Pm_dt_w   = PAR + off[21];
    const float* Pm_dt_b   = PAR + off[22];
    const float* Pm_A_log  = PAR + off[23];
    const float* Pm_D      = PAR + off[24];
    const float* Pm_out_w  = PAR + off[25];
    const float* Pnorm_s   = PAR + off[26];
    const float* Pnorm_b   = PAR + off[27];

    // input proj: h = x @ proj_w.T + proj_b
    launch_gemm(Px, Pproj_w, Pproj_b, nullptr, H, TOK, 128, 256, 256, 0, stream);

    const char sched[9] = "TMMMTMMM";
    int ti = 0, mi = 0;
    for (int li = 0; li < 8; ++li) {
        if (sched[li] == 'T') {
            launch_gemm(H, Pt_in_w + (size_t)ti * 384 * 128, Pt_in_b + ti * 384,
                        nullptr, T1, TOK, 384, 128, 128, 0, stream);
            hipLaunchKernelGGL(attn_kernel, dim3(64, 16), dim3(128), 0, stream, T1, T2);
            launch_gemm(T2, Pt_out_w + (size_t)ti * 128 * 128, Pt_out_b + ti * 128,
                        H, T3, TOK, 128, 128, 128, 0, stream);
            hipLaunchKernelGGL(ln_kernel, dim3(TOK / 4), dim3(256), 0, stream,
                               T3, Pt_n1_s + ti * 128, Pt_n1_b + ti * 128, H,
                               (void*)nullptr, FLAG);
            launch_gemm(H, Pt_ff1_w + (size_t)ti * 512 * 128, Pt_ff1_b + ti * 512,
                        nullptr, T1, TOK, 512, 128, 128, 1, stream);
            launch_gemm(T1, Pt_ff2_w + (size_t)ti * 128 * 512, Pt_ff2_b + ti * 128,
                        H, T3, TOK, 128, 512, 512, 0, stream);
            hipLaunchKernelGGL(ln_kernel, dim3(TOK / 4), dim3(256), 0, stream,
                               T3, Pt_n2_s + ti * 128, Pt_n2_b + ti * 128, H,
                               (void*)nullptr, FLAG);
            ++ti;
        } else {
            hipLaunchKernelGGL(ln_kernel, dim3(TOK / 4), dim3(256), 0, stream,
                               H, Pm_norm_s + mi * 128, Pm_norm_b + mi * 128, XN,
                               (void*)nullptr, FLAG);
            launch_gemm(XN, Pm_in_w + (size_t)mi * 512 * 128, nullptr, nullptr,
                        T1, TOK, 512, 128, 128, 0, stream);
            hipLaunchKernelGGL(conv_silu_kernel, dim3(TOK), dim3(256), 0, stream,
                               T1, Pm_conv_w + mi * 256 * 4, Pm_conv_b + mi * 256, T2);
            launch_gemm(T2, Pm_xproj_w + (size_t)mi * 40 * 256, nullptr, nullptr,
                        DBC, TOK, 40, 256, 256, 0, stream);
            launch_gemm(DBC, Pm_dt_w + (size_t)mi * 256 * 8, Pm_dt_b + mi * 256, nullptr,
                        DT, TOK, 256, 8, 40, 2, stream);
            hipLaunchKernelGGL(scan_a, dim3(BATCH * 16 * NCHUNK), dim3(256), 0, stream,
                               DT, T2, DBC, Pm_A_log + (size_t)mi * 256 * 16, PS);
            hipLaunchKernelGGL(scan_b, dim3(64), dim3(256), 0, stream, PS, H0);
            hipLaunchKernelGGL(scan_c, dim3(BATCH * 16 * NCHUNK), dim3(256), 0, stream,
                               DT, T2, DBC, Pm_A_log + (size_t)mi * 256 * 16, H0, T1,
                               Pm_D + mi * 256, Y);
            launch_gemm(Y, Pm_out_w + (size_t)mi * 128 * 256, nullptr, H, H,
                        TOK, 128, 256, 256, 0, stream);
            ++mi;
        }
    }
    hipLaunchKernelGGL(ln_kernel, dim3(TOK / 4), dim3(256), 0, stream,
                       H, Pnorm_s, Pnorm_b, (float*)nullptr, d_out, FLAG);
}

// Round 3
// 1603.398 us; speedup vs baseline: 1.7659x; 1.7659x over previous
//
#include <hip/hip_runtime.h>
#include <hip/hip_bf16.h>
#include <math.h>

using bf16 = __hip_bfloat16;

typedef __attribute__((ext_vector_type(8))) short short8;
typedef __attribute__((ext_vector_type(4))) short short4v;
typedef __attribute__((ext_vector_type(4))) float float4v;

#define BATCH 4
#define SEQL 2048
#define TOK (BATCH * SEQL)     // 8192
#define DMODEL 128
#define DINNER 256
#define NSTATE 16
#define NCHUNK 32
#define TCHUNK 64              // 32*64 = 2048

#define NPAR 28
#define PAR_TOTAL 3227264

struct Srcs { const void* p[NPAR]; int off[NPAR + 1]; };

// fp32 -> bf16 (RNE)
__device__ __forceinline__ short f2b(float f) {
    unsigned u = __builtin_bit_cast(unsigned, f);
    unsigned r = (u + 0x7FFF + ((u >> 16) & 1)) >> 16;
    return (short)r;
}

// ---------------------------------------------------------------------------
// Decide whether inputs are bf16 (flag=1) or fp32 (flag=0).
__global__ __launch_bounds__(128) void sniff_kernel(const unsigned int* __restrict__ xw,
                                                    int* __restrict__ flag) {
    __shared__ int cnt;
    if (threadIdx.x == 0) cnt = 0;
    __syncthreads();
    unsigned u = xw[threadIdx.x];
    unsigned elo = (u >> 7) & 0xFF;
    unsigned ehi = (u >> 23) & 0xFF;
    int ok = (elo >= 100 && elo <= 140) && (ehi >= 100 && ehi <= 140);
    if (ok) atomicAdd(&cnt, 1);
    __syncthreads();
    if (threadIdx.x == 0) *flag = (cnt >= 96) ? 1 : 0;
}

// Convert all 28 tensors into one fp32 parameter block.
__global__ __launch_bounds__(256) void cvt_all(Srcs s, const int* __restrict__ flag,
                                               float* __restrict__ dst, int total) {
    int idx = blockIdx.x * 256 + threadIdx.x;
    if (idx >= total) return;
    int t = 0;
    while (idx >= s.off[t + 1]) ++t;
    int j = idx - s.off[t];
    float v;
    if (*flag) v = __bfloat162float(((const bf16*)s.p[t])[j]);
    else       v = ((const float*)s.p[t])[j];
    dst[idx] = v;
}

// ---------------------------------------------------------------------------
// MFMA GEMM: C[m,n] = act( A[m,:K] . W[n,:K] + bias[n] ) + res[m,n]
// A fp32 (lda), W fp32 (N,K) row-major. 64x64 tile, 4 waves, bf16 MFMA.
// act: 0 none, 1 relu, 2 softplus
__global__ __launch_bounds__(256) void gemm_mfma(const float* __restrict__ A,
                                                 const float* __restrict__ W,
                                                 const float* __restrict__ bias,
                                                 const float* __restrict__ res,
                                                 float* __restrict__ C,
                                                 int M, int N, int K, int lda, int act) {
    __shared__ short As[64][72];
    __shared__ short Bs[64][72];
    const int bm = blockIdx.y * 64, bn = blockIdx.x * 64;
    const int tid = threadIdx.x;
    const int w = tid >> 6, lane = tid & 63;
    const int la = lane & 15, quad = lane >> 4;
    const int srow = tid >> 2, sk0 = (tid & 3) * 16;
    float4v acc[4] = {};
    for (int kb = 0; kb < K; kb += 64) {
        #pragma unroll
        for (int hh = 0; hh < 2; ++hh) {
            int k0 = sk0 + hh * 8;
            float va[8], vb[8];
            const int nrow = bn + srow;
            #pragma unroll
            for (int j = 0; j < 8; ++j) {
                int kk = kb + k0 + j;
                va[j] = (kk < K) ? A[(size_t)(bm + srow) * lda + kk] : 0.f;
                vb[j] = (nrow < N && kk < K) ? W[(size_t)nrow * K + kk] : 0.f;
            }
            short4v a0 = {f2b(va[0]), f2b(va[1]), f2b(va[2]), f2b(va[3])};
            short4v a1 = {f2b(va[4]), f2b(va[5]), f2b(va[6]), f2b(va[7])};
            short4v b0 = {f2b(vb[0]), f2b(vb[1]), f2b(vb[2]), f2b(vb[3])};
            short4v b1 = {f2b(vb[4]), f2b(vb[5]), f2b(vb[6]), f2b(vb[7])};
            *(short4v*)&As[srow][k0]     = a0;
            *(short4v*)&As[srow][k0 + 4] = a1;
            *(short4v*)&Bs[srow][k0]     = b0;
            *(short4v*)&Bs[srow][k0 + 4] = b1;
        }
        __syncthreads();
        #pragma unroll
        for (int ks = 0; ks < 2; ++ks) {
            short8 af;
            *(short4v*)&af       = *(short4v*)&As[w * 16 + la][ks * 32 + quad * 8];
            *((short4v*)&af + 1) = *(short4v*)&As[w * 16 + la][ks * 32 + quad * 8 + 4];
            #pragma unroll
            for (int f = 0; f < 4; ++f) {
                short8 bf;
                *(short4v*)&bf       = *(short4v*)&Bs[f * 16 + la][ks * 32 + quad * 8];
                *((short4v*)&bf + 1) = *(short4v*)&Bs[f * 16 + la][ks * 32 + quad * 8 + 4];
                acc[f] = __builtin_amdgcn_mfma_f32_16x16x32_bf16(af, bf, acc[f], 0, 0, 0);
            }
        }
        __syncthreads();
    }
    #pragma unroll
    for (int f = 0; f < 4; ++f) {
        int n = bn + f * 16 + la;
        if (n >= N) continue;
        float bv = bias ? bias[n] : 0.f;
        #pragma unroll
        for (int i = 0; i < 4; ++i) {
            int m = bm + w * 16 + quad * 4 + i;
            float v = acc[f][i] + bv;
            if (act == 1) v = fmaxf(v, 0.f);
            else if (act == 2) v = (v > 20.f) ? v : log1pf(__expf(v));
            if (res) v += res[(size_t)m * N + n];
            C[(size_t)m * N + n] = v;
        }
    }
}

// ---------------------------------------------------------------------------
// LayerNorm over last dim (128). One wave per row, 4 rows per block.
__global__ __launch_bounds__(256) void ln_kernel(const float* __restrict__ in,
                                                 const float* __restrict__ s,
                                                 const float* __restrict__ bta,
                                                 float* __restrict__ outf,
                                                 void* __restrict__ outd,
                                                 const int* __restrict__ flag) {
    int wave = threadIdx.x >> 6, lane = threadIdx.x & 63;
    size_t row = (size_t)blockIdx.x * 4 + wave;
    const float* x = in + row * 128;
    float v0 = x[lane], v1 = x[lane + 64];
    float sum = v0 + v1;
    #pragma unroll
    for (int off = 32; off; off >>= 1) sum += __shfl_xor(sum, off);
    float mu = sum * (1.f / 128.f);
    float d0 = v0 - mu, d1 = v1 - mu;
    float vs = d0 * d0 + d1 * d1;
    #pragma unroll
    for (int off = 32; off; off >>= 1) vs += __shfl_xor(vs, off);
    float rstd = rsqrtf(vs * (1.f / 128.f) + 1e-5f);
    float y0 = d0 * rstd * s[lane] + bta[lane];
    float y1 = d1 * rstd * s[lane + 64] + bta[lane + 64];
    if (outf) {
        outf[row * 128 + lane] = y0; outf[row * 128 + lane + 64] = y1;
    } else if (*flag) {
        ((bf16*)outd)[row * 128 + lane] = __float2bfloat16(y0);
        ((bf16*)outd)[row * 128 + lane + 64] = __float2bfloat16(y1);
    } else {
        ((float*)outd)[row * 128 + lane] = y0;
        ((float*)outd)[row * 128 + lane + 64] = y1;
    }
}

// ---------------------------------------------------------------------------
// MFMA flash attention (no mask). qkv (TOK,384) fp32; out (TOK,128) fp32.
// grid (SEQL/64, 16). block 256 = 4 waves; wave owns 16 Q rows; K-tile 64.
__global__ __launch_bounds__(256) void attn_mfma(const float* __restrict__ qkv,
                                                 float* __restrict__ out) {
    __shared__ short Ks[64][36];       // K[key][d]
    __shared__ short Vt[32][76];       // V^T[d][n]
    __shared__ short Pb[4][16][72];    // per-wave P[m][n]
    const int bh = blockIdx.y, b = bh >> 2, h = bh & 3;
    const int q0 = blockIdx.x * 64;
    const int tid = threadIdx.x, w = tid >> 6, lane = tid & 63;
    const int la = lane & 15, quad = lane >> 4;
    const size_t tokbase = (size_t)b * SEQL;
    const int hcol = h * 32;
    const float SCL = 0.17677669529663687f;   // 1/sqrt(32)

    // Q fragment (A-layout): Q[q0+w*16+la][quad*8 + j]
    short8 qa;
    {
        const float* qp = qkv + (tokbase + q0 + w * 16 + la) * 384 + hcol + quad * 8;
        float4v q1 = *(const float4v*)qp;
        float4v q2 = *(const float4v*)(qp + 4);
        short4v s0 = {f2b(q1[0] * SCL), f2b(q1[1] * SCL), f2b(q1[2] * SCL), f2b(q1[3] * SCL)};
        short4v s1 = {f2b(q2[0] * SCL), f2b(q2[1] * SCL), f2b(q2[2] * SCL), f2b(q2[3] * SCL)};
        *(short4v*)&qa = s0;
        *((short4v*)&qa + 1) = s1;
    }
    float4v o0 = {}, o1 = {};
    float mr[4], lr[4];
    #pragma unroll
    for (int i = 0; i < 4; ++i) { mr[i] = -1e30f; lr[i] = 0.f; }

    const int srow = tid >> 2, sd0 = (tid & 3) * 8;
    for (int kt = 0; kt < SEQL; kt += 64) {
        // stage K tile [64][32] as bf16
        {
            const float* kp = qkv + (tokbase + kt + srow) * 384 + 128 + hcol + sd0;
            float4v k1 = *(const float4v*)kp;
            float4v k2 = *(const float4v*)(kp + 4);
            short4v s0 = {f2b(k1[0]), f2b(k1[1]), f2b(k1[2]), f2b(k1[3])};
            short4v s1 = {f2b(k2[0]), f2b(k2[1]), f2b(k2[2]), f2b(k2[3])};
            *(short4v*)&Ks[srow][sd0]     = s0;
            *(short4v*)&Ks[srow][sd0 + 4] = s1;
        }
        // stage V tile transposed [32 d][64 n]
        {
            const float* vp = qkv + (tokbase + kt + srow) * 384 + 256 + hcol + sd0;
            float4v v1 = *(const float4v*)vp;
            float4v v2 = *(const float4v*)(vp + 4);
            #pragma unroll
            for (int j = 0; j < 4; ++j) Vt[sd0 + j][srow]     = f2b(v1[j]);
            #pragma unroll
            for (int j = 0; j < 4; ++j) Vt[sd0 + 4 + j][srow] = f2b(v2[j]);
        }
        __syncthreads();

        // scores: 16 q-rows x 64 keys (4 C-frags)
        float4v sc[4];
        #pragma unroll
        for (int f = 0; f < 4; ++f) {
            short8 kb;
            *(short4v*)&kb       = *(short4v*)&Ks[f * 16 + la][quad * 8];
            *((short4v*)&kb + 1) = *(short4v*)&Ks[f * 16 + la][quad * 8 + 4];
            float4v z = {};
            sc[f] = __builtin_amdgcn_mfma_f32_16x16x32_bf16(qa, kb, z, 0, 0, 0);
        }
        // online softmax: rows live at row=quad*4+i across 16 lanes (la)
        float al[4];
        #pragma unroll
        for (int i = 0; i < 4; ++i) {
            float mx = fmaxf(fmaxf(sc[0][i], sc[1][i]), fmaxf(sc[2][i], sc[3][i]));
            mx = fmaxf(mx, __shfl_xor(mx, 1));
            mx = fmaxf(mx, __shfl_xor(mx, 2));
            mx = fmaxf(mx, __shfl_xor(mx, 4));
            mx = fmaxf(mx, __shfl_xor(mx, 8));
            float mn = fmaxf(mr[i], mx);
            al[i] = __expf(mr[i] - mn);
            mr[i] = mn;
            float rs = 0.f;
            #pragma unroll
            for (int f = 0; f < 4; ++f) {
                float pp = __expf(sc[f][i] - mn);
                sc[f][i] = pp; rs += pp;
            }
            rs += __shfl_xor(rs, 1);
            rs += __shfl_xor(rs, 2);
            rs += __shfl_xor(rs, 4);
            rs += __shfl_xor(rs, 8);
            lr[i] = lr[i] * al[i] + rs;
            o0[i] *= al[i];
            o1[i] *= al[i];
            // write P row (C-layout -> [m][n] in LDS)
            #pragma unroll
            for (int f = 0; f < 4; ++f)
                Pb[w][quad * 4 + i][f * 16 + la] = f2b(sc[f][i]);
        }
        // PV: O[m][d] += P[m][n] V[n][d]
        #pragma unroll
        for (int c = 0; c < 2; ++c) {
            short8 pa;
            *(short4v*)&pa       = *(short4v*)&Pb[w][la][c * 32 + quad * 8];
            *((short4v*)&pa + 1) = *(short4v*)&Pb[w][la][c * 32 + quad * 8 + 4];
            short8 vb0, vb1;
            *(short4v*)&vb0       = *(short4v*)&Vt[la][c * 32 + quad * 8];
            *((short4v*)&vb0 + 1) = *(short4v*)&Vt[la][c * 32 + quad * 8 + 4];
            *(short4v*)&vb1       = *(short4v*)&Vt[16 + la][c * 32 + quad * 8];
            *((short4v*)&vb1 + 1) = *(short4v*)&Vt[16 + la][c * 32 + quad * 8 + 4];
            o0 = __builtin_amdgcn_mfma_f32_16x16x32_bf16(pa, vb0, o0, 0, 0, 0);
            o1 = __builtin_amdgcn_mfma_f32_16x16x32_bf16(pa, vb1, o1, 0, 0, 0);
        }
        __syncthreads();
    }
    #pragma unroll
    for (int i = 0; i < 4; ++i) {
        float li = 1.f / lr[i];
        float* op = out + (tokbase + q0 + w * 16 + quad * 4 + i) * 128 + hcol;
        op[la]      = o0[i] * li;
        op[16 + la] = o1[i] * li;
    }
}

// ---------------------------------------------------------------------------
// causal depthwise conv (K=4) + silu. xz (TOK,512) fp32, x part cols [0,256).
__global__ __launch_bounds__(256) void conv_silu_kernel(const float* __restrict__ xz,
                                                        const float* __restrict__ w,
                                                        const float* __restrict__ cb,
                                                        float* __restrict__ out) {
    int idx = blockIdx.x * 256 + threadIdx.x;
    int d = idx & 255; int t = (idx >> 8) & (SEQL - 1); int b = idx >> 19;
    float acc = cb[d];
    #pragma unroll
    for (int k = 0; k < 4; ++k) {
        int tt = t - 3 + k;
        if (tt >= 0)
            acc += xz[((size_t)b * SEQL + tt) * 512 + d] * w[d * 4 + k];
    }
    out[idx] = acc / (1.f + __expf(-acc));
}

// ---------------------------------------------------------------------------
// SSM chunked scan.
__global__ __launch_bounds__(256) void scan_a(const float* __restrict__ dt,
                                              const float* __restrict__ xc,
                                              const float* __restrict__ dbc,
                                              const float* __restrict__ A_log,
                                              float* __restrict__ PS) {
    const int c = blockIdx.x & (NCHUNK - 1);
    const int dg = (blockIdx.x >> 5) & 15;
    const int b = blockIdx.x >> 9;
    const int dl = threadIdx.x >> 4, n = threadIdx.x & 15;
    const int d = dg * 16 + dl;
    const float Av = -__expf(A_log[d * 16 + n]);
    float P = 1.f, S = 0.f;
    const size_t tbase = (size_t)b * SEQL + c * TCHUNK;
    for (int t = 0; t < TCHUNK; ++t) {
        float dtv = dt[(tbase + t) * 256 + d];
        float xv = xc[(tbase + t) * 256 + d];
        float Bv = dbc[(tbase + t) * 40 + 8 + n];
        float a = __expf(dtv * Av);
        P *= a;
        S = a * S + dtv * xv * Bv;
    }
    size_t o = (((size_t)b * NCHUNK + c) * 256 + d) * 16 + n;
    PS[o] = S;
    PS[o + (size_t)BATCH * NCHUNK * 256 * 16] = P;
}

__global__ __launch_bounds__(256) void scan_b(const float* __restrict__ PS,
                                              float* __restrict__ H0) {
    int idx = blockIdx.x * 256 + threadIdx.x;   // BATCH*256*16 = 16384
    int n = idx & 15; int d = (idx >> 4) & 255; int b = idx >> 12;
    float h = 0.f;
    const size_t poff = (size_t)BATCH * NCHUNK * 256 * 16;
    for (int c = 0; c < NCHUNK; ++c) {
        size_t o = (((size_t)b * NCHUNK + c) * 256 + d) * 16 + n;
        H0[o] = h;
        h = PS[o + poff] * h + PS[o];
    }
}

__global__ __launch_bounds__(256) void scan_c(const float* __restrict__ dt,
                                              const float* __restrict__ xc,
                                              const float* __restrict__ dbc,
                                              const float* __restrict__ A_log,
                                              const float* __restrict__ H0,
                                              const float* __restrict__ xz,
                                              const float* __restrict__ Dp,
                                              float* __restrict__ y) {
    const int c = blockIdx.x & (NCHUNK - 1);
    const int dg = (blockIdx.x >> 5) & 15;
    const int b = blockIdx.x >> 9;
    const int dl = threadIdx.x >> 4, n = threadIdx.x & 15;
    const int d = dg * 16 + dl;
    const float Av = -__expf(A_log[d * 16 + n]);
    const float Dv = Dp[d];
    size_t o0 = (((size_t)b * NCHUNK + c) * 256 + d) * 16 + n;
    float h = H0[o0];
    const size_t tbase = (size_t)b * SEQL + c * TCHUNK;
    for (int t = 0; t < TCHUNK; ++t) {
        float dtv = dt[(tbase + t) * 256 + d];
        float xv = xc[(tbase + t) * 256 + d];
        float Bv = dbc[(tbase + t) * 40 + 8 + n];
        float Cv = dbc[(tbase + t) * 40 + 24 + n];
        float a = __expf(dtv * Av);
        h = a * h + dtv * xv * Bv;
        float p = h * Cv;
        p += __shfl_xor(p, 1); p += __shfl_xor(p, 2);
        p += __shfl_xor(p, 4); p += __shfl_xor(p, 8);
        if (n == 0) {
            float zv = xz[(tbase + t) * 512 + 256 + d];
            float sz = zv / (1.f + __expf(-zv));
            y[(tbase + t) * 256 + d] = (p + xv * Dv) * sz;
        }
    }
}

// ---------------------------------------------------------------------------
static inline void launch_gemm(const float* A, const float* W, const float* bias,
                               const float* res, float* C, int M, int N, int K,
                               int lda, int act, hipStream_t s) {
    dim3 g((N + 63) / 64, M / 64);
    hipLaunchKernelGGL(gemm_mfma, g, dim3(256), 0, s, A, W, bias, res, C, M, N, K, lda, act);
}

static const int kSizes[NPAR] = {
    2097152, 32768, 128, 98304, 768, 32768, 256, 131072, 1024, 131072, 256,
    256, 256, 256, 256, 768, 768, 393216, 6144, 1536, 61440, 12288, 1536,
    24576, 1536, 196608, 128, 128
};

extern "C" void kernel_launch(void* const* d_in, const int* in_sizes, int n_in,
                              void* d_out, int out_size, void* d_ws, size_t ws_size,
                              hipStream_t stream) {
    Srcs srcs;
    int off[NPAR + 1];
    off[0] = 0;
    for (int i = 0; i < NPAR; ++i) {
        srcs.p[i] = d_in[i];
        off[i + 1] = off[i] + kSizes[i];
        srcs.off[i] = off[i];
    }
    srcs.off[NPAR] = off[NPAR];

    int* FLAG = (int*)d_ws;
    float* PAR = (float*)((char*)d_ws + 256);
    float* p = PAR + PAR_TOTAL;
    float* H   = p; p += (size_t)TOK * 128;
    float* XN  = p; p += (size_t)TOK * 128;
    float* T1  = p; p += (size_t)TOK * 512;
    float* T2  = p; p += (size_t)TOK * 256;
    float* T3  = p; p += (size_t)TOK * 128;
    float* DBC = p; p += (size_t)TOK * 40;
    float* DT  = p; p += (size_t)TOK * 256;
    float* Y   = p; p += (size_t)TOK * 256;
    float* PS  = p; p += (size_t)2 * BATCH * NCHUNK * 256 * 16;
    float* H0  = p; p += (size_t)BATCH * NCHUNK * 256 * 16;

    hipLaunchKernelGGL(sniff_kernel, dim3(1), dim3(128), 0, stream,
                       (const unsigned int*)d_in[0], FLAG);
    hipLaunchKernelGGL(cvt_all, dim3((PAR_TOTAL + 255) / 256), dim3(256), 0, stream,
                       srcs, FLAG, PAR, PAR_TOTAL);

    const float* Px        = PAR + off[0];
    const float* Pproj_w   = PAR + off[1];
    const float* Pproj_b   = PAR + off[2];
    const float* Pt_in_w   = PAR + off[3];
    const float* Pt_in_b   = PAR + off[4];
    const float* Pt_out_w  = PAR + off[5];
    const float* Pt_out_b  = PAR + off[6];
    const float* Pt_ff1_w  = PAR + off[7];
    const float* Pt_ff1_b  = PAR + off[8];
    const float* Pt_ff2_w  = PAR + off[9];
    const float* Pt_ff2_b  = PAR + off[10];
    const float* Pt_n1_s   = PAR + off[11];
    const float* Pt_n1_b   = PAR + off[12];
    const float* Pt_n2_s   = PAR + off[13];
    const float* Pt_n2_b   = PAR + off[14];
    const float* Pm_norm_s = PAR + off[15];
    const float* Pm_norm_b = PAR + off[16];
    const float* Pm_in_w   = PAR + off[17];
    const float* Pm_conv_w = PAR + off[18];
    const float* Pm_conv_b = PAR + off[19];
    const float* Pm_xproj_w= PAR + off[20];
    const float* Pm_dt_w   = PAR + off[21];
    const float* Pm_dt_b   = PAR + off[22];
    const float* Pm_A_log  = PAR + off[23];
    const float* Pm_D      = PAR + off[24];
    const float* Pm_out_w  = PAR + off[25];
    const float* Pnorm_s   = PAR + off[26];
    const float* Pnorm_b   = PAR + off[27];

    launch_gemm(Px, Pproj_w, Pproj_b, nullptr, H, TOK, 128, 256, 256, 0, stream);

    const char sched[9] = "TMMMTMMM";
    int ti = 0, mi = 0;
    for (int li = 0; li < 8; ++li) {
        if (sched[li] == 'T') {
            launch_gemm(H, Pt_in_w + (size_t)ti * 384 * 128, Pt_in_b + ti * 384,
                        nullptr, T1, TOK, 384, 128, 128, 0, stream);
            hipLaunchKernelGGL(attn_mfma, dim3(SEQL / 64, 16), dim3(256), 0, stream, T1, T2);
            launch_gemm(T2, Pt_out_w + (size_t)ti * 128 * 128, Pt_out_b + ti * 128,
                        H, T3, TOK, 128, 128, 128, 0, stream);
            hipLaunchKernelGGL(ln_kernel, dim3(TOK / 4), dim3(256), 0, stream,
                               T3, Pt_n1_s + ti * 128, Pt_n1_b + ti * 128, H,
                               (void*)nullptr, FLAG);
            launch_gemm(H, Pt_ff1_w + (size_t)ti * 512 * 128, Pt_ff1_b + ti * 512,
                        nullptr, T1, TOK, 512, 128, 128, 1, stream);
            launch_gemm(T1, Pt_ff2_w + (size_t)ti * 128 * 512, Pt_ff2_b + ti * 128,
                        H, T3, TOK, 128, 512, 512, 0, stream);
            hipLaunchKernelGGL(ln_kernel, dim3(TOK / 4), dim3(256), 0, stream,
                               T3, Pt_n2_s + ti * 128, Pt_n2_b + ti * 128, H,
                               (void*)nullptr, FLAG);
            ++ti;
        } else {
            hipLaunchKernelGGL(ln_kernel, dim3(TOK / 4), dim3(256), 0, stream,
                               H, Pm_norm_s + mi * 128, Pm_norm_b + mi * 128, XN,
                               (void*)nullptr, FLAG);
            launch_gemm(XN, Pm_in_w + (size_t)mi * 512 * 128, nullptr, nullptr,
                        T1, TOK, 512, 128, 128, 0, stream);
            hipLaunchKernelGGL(conv_silu_kernel, dim3(TOK), dim3(256), 0, stream,
                               T1, Pm_conv_w + mi * 256 * 4, Pm_conv_b + mi * 256, T2);
            launch_gemm(T2, Pm_xproj_w + (size_t)mi * 40 * 256, nullptr, nullptr,
                        DBC, TOK, 40, 256, 256, 0, stream);
            launch_gemm(DBC, Pm_dt_w + (size_t)mi * 256 * 8, Pm_dt_b + mi * 256, nullptr,
                        DT, TOK, 256, 8, 40, 2, stream);
            hipLaunchKernelGGL(scan_a, dim3(BATCH * 16 * NCHUNK), dim3(256), 0, stream,
                               DT, T2, DBC, Pm_A_log + (size_t)mi * 256 * 16, PS);
            hipLaunchKernelGGL(scan_b, dim3(64), dim3(256), 0, stream, PS, H0);
            hipLaunchKernelGGL(scan_c, dim3(BATCH * 16 * NCHUNK), dim3(256), 0, stream,
                               DT, T2, DBC, Pm_A_log + (size_t)mi * 256 * 16, H0, T1,
                               Pm_D + mi * 256, Y);
            launch_gemm(Y, Pm_out_w + (size_t)mi * 128 * 256, nullptr, H, H,
                        TOK, 128, 256, 256, 0, stream);
            ++mi;
        }
    }
    hipLaunchKernelGGL(ln_kernel, dim3(TOK / 4), dim3(256), 0, stream,
                       H, Pnorm_s, Pnorm_b, (float*)nullptr, d_out, FLAG);
}

// Round 4
// 1108.613 us; speedup vs baseline: 2.5541x; 1.4463x over previous
//
#include <hip/hip_runtime.h>
#include <hip/hip_bf16.h>
#include <math.h>

using bf16 = __hip_bfloat16;

typedef __attribute__((ext_vector_type(8))) short short8;
typedef __attribute__((ext_vector_type(4))) short short4v;
typedef __attribute__((ext_vector_type(4))) float float4v;

#define BATCH 4
#define SEQL 2048
#define TOK (BATCH * SEQL)     // 8192
#define NCHUNK 32
#define TCHUNK 64              // 32*64 = 2048

#define NPAR 28
#define PAR_TOTAL 3227264

struct Srcs { const void* p[NPAR]; int off[NPAR + 1]; };

// fp32 -> bf16 (RNE)
__device__ __forceinline__ short f2b(float f) {
    unsigned u = __builtin_bit_cast(unsigned, f);
    unsigned r = (u + 0x7FFF + ((u >> 16) & 1)) >> 16;
    return (short)r;
}
__device__ __forceinline__ float b2f(short s) {
    unsigned u = ((unsigned)(unsigned short)s) << 16;
    return __builtin_bit_cast(float, u);
}

// ---------------------------------------------------------------------------
__global__ __launch_bounds__(128) void sniff_kernel(const unsigned int* __restrict__ xw,
                                                    int* __restrict__ flag) {
    __shared__ int cnt;
    if (threadIdx.x == 0) cnt = 0;
    __syncthreads();
    unsigned u = xw[threadIdx.x];
    unsigned elo = (u >> 7) & 0xFF;
    unsigned ehi = (u >> 23) & 0xFF;
    int ok = (elo >= 100 && elo <= 140) && (ehi >= 100 && ehi <= 140);
    if (ok) atomicAdd(&cnt, 1);
    __syncthreads();
    if (threadIdx.x == 0) *flag = (cnt >= 96) ? 1 : 0;
}

// Convert all 28 tensors into fp32 + bf16 parameter blocks.
__global__ __launch_bounds__(256) void cvt_all(Srcs s, const int* __restrict__ flag,
                                               float* __restrict__ dst,
                                               short* __restrict__ dstb, int total) {
    int idx = blockIdx.x * 256 + threadIdx.x;
    if (idx >= total) return;
    int t = 0;
    while (idx >= s.off[t + 1]) ++t;
    int j = idx - s.off[t];
    if (*flag) {
        short raw = ((const short*)s.p[t])[j];
        dstb[idx] = raw;
        dst[idx] = b2f(raw);
    } else {
        float v = ((const float*)s.p[t])[j];
        dst[idx] = v;
        dstb[idx] = f2b(v);
    }
}

// ---------------------------------------------------------------------------
// MFMA GEMM, bf16 operands: C = act(A[m,:K].W[n,:K] + bias[n]) + res
// A bf16 (lda), W bf16 (N,K). Outputs: Cf fp32 (opt), Cb bf16 (opt).
// act: 0 none, 1 relu, 2 softplus
__global__ __launch_bounds__(256) void gemm_mfma(const short* __restrict__ A,
                                                 const short* __restrict__ W,
                                                 const float* __restrict__ bias,
                                                 const float* __restrict__ res,
                                                 float* __restrict__ Cf,
                                                 short* __restrict__ Cb,
                                                 int M, int N, int K, int lda, int act) {
    __shared__ short As[64][76];
    __shared__ short Bs[64][76];
    const int bm = blockIdx.y * 64, bn = blockIdx.x * 64;
    const int tid = threadIdx.x;
    const int w = tid >> 6, lane = tid & 63;
    const int la = lane & 15, quad = lane >> 4;
    const int srow = tid >> 2, sk0 = (tid & 3) * 16;
    const int nrow = bn + srow;
    float4v acc[4] = {};
    for (int kb = 0; kb < K; kb += 64) {
        if (kb + 64 <= K) {
            const short* ap = A + (size_t)(bm + srow) * lda + kb + sk0;
            short8 av0 = *(const short8*)ap;
            short8 av1 = *(const short8*)(ap + 8);
            short8 bv0 = {}, bv1 = {};
            if (nrow < N) {
                const short* wp = W + (size_t)nrow * K + kb + sk0;
                bv0 = *(const short8*)wp;
                bv1 = *(const short8*)(wp + 8);
            }
            *(short4v*)&As[srow][sk0]      = *(short4v*)&av0;
            *(short4v*)&As[srow][sk0 + 4]  = *((short4v*)&av0 + 1);
            *(short4v*)&As[srow][sk0 + 8]  = *(short4v*)&av1;
            *(short4v*)&As[srow][sk0 + 12] = *((short4v*)&av1 + 1);
            *(short4v*)&Bs[srow][sk0]      = *(short4v*)&bv0;
            *(short4v*)&Bs[srow][sk0 + 4]  = *((short4v*)&bv0 + 1);
            *(short4v*)&Bs[srow][sk0 + 8]  = *(short4v*)&bv1;
            *(short4v*)&Bs[srow][sk0 + 12] = *((short4v*)&bv1 + 1);
        } else {
            #pragma unroll
            for (int j = 0; j < 16; ++j) {
                int kk = kb + sk0 + j;
                As[srow][sk0 + j] = (kk < K) ? A[(size_t)(bm + srow) * lda + kk] : (short)0;
                Bs[srow][sk0 + j] = (nrow < N && kk < K) ? W[(size_t)nrow * K + kk] : (short)0;
            }
        }
        __syncthreads();
        #pragma unroll
        for (int ks = 0; ks < 2; ++ks) {
            short8 af;
            *(short4v*)&af       = *(short4v*)&As[w * 16 + la][ks * 32 + quad * 8];
            *((short4v*)&af + 1) = *(short4v*)&As[w * 16 + la][ks * 32 + quad * 8 + 4];
            #pragma unroll
            for (int f = 0; f < 4; ++f) {
                short8 bf;
                *(short4v*)&bf       = *(short4v*)&Bs[f * 16 + la][ks * 32 + quad * 8];
                *((short4v*)&bf + 1) = *(short4v*)&Bs[f * 16 + la][ks * 32 + quad * 8 + 4];
                acc[f] = __builtin_amdgcn_mfma_f32_16x16x32_bf16(af, bf, acc[f], 0, 0, 0);
            }
        }
        __syncthreads();
    }
    #pragma unroll
    for (int f = 0; f < 4; ++f) {
        int n = bn + f * 16 + la;
        if (n >= N) continue;
        float bv = bias ? bias[n] : 0.f;
        #pragma unroll
        for (int i = 0; i < 4; ++i) {
            int m = bm + w * 16 + quad * 4 + i;
            float v = acc[f][i] + bv;
            if (act == 1) v = fmaxf(v, 0.f);
            else if (act == 2) v = (v > 20.f) ? v : log1pf(__expf(v));
            if (res) v += res[(size_t)m * N + n];
            if (Cf) Cf[(size_t)m * N + n] = v;
            if (Cb) Cb[(size_t)m * N + n] = f2b(v);
        }
    }
}

// ---------------------------------------------------------------------------
// LayerNorm over last dim (128). outf fp32 (opt), outb bf16 (opt),
// outd final output typed by flag (opt).
__global__ __launch_bounds__(256) void ln_kernel(const float* __restrict__ in,
                                                 const float* __restrict__ s,
                                                 const float* __restrict__ bta,
                                                 float* __restrict__ outf,
                                                 short* __restrict__ outb,
                                                 void* __restrict__ outd,
                                                 const int* __restrict__ flag) {
    int wave = threadIdx.x >> 6, lane = threadIdx.x & 63;
    size_t row = (size_t)blockIdx.x * 4 + wave;
    const float* x = in + row * 128;
    float v0 = x[lane], v1 = x[lane + 64];
    float sum = v0 + v1;
    #pragma unroll
    for (int off = 32; off; off >>= 1) sum += __shfl_xor(sum, off);
    float mu = sum * (1.f / 128.f);
    float d0 = v0 - mu, d1 = v1 - mu;
    float vs = d0 * d0 + d1 * d1;
    #pragma unroll
    for (int off = 32; off; off >>= 1) vs += __shfl_xor(vs, off);
    float rstd = rsqrtf(vs * (1.f / 128.f) + 1e-5f);
    float y0 = d0 * rstd * s[lane] + bta[lane];
    float y1 = d1 * rstd * s[lane + 64] + bta[lane + 64];
    if (outf) { outf[row * 128 + lane] = y0; outf[row * 128 + lane + 64] = y1; }
    if (outb) { outb[row * 128 + lane] = f2b(y0); outb[row * 128 + lane + 64] = f2b(y1); }
    if (outd) {
        if (*flag) {
            ((bf16*)outd)[row * 128 + lane] = __float2bfloat16(y0);
            ((bf16*)outd)[row * 128 + lane + 64] = __float2bfloat16(y1);
        } else {
            ((float*)outd)[row * 128 + lane] = y0;
            ((float*)outd)[row * 128 + lane + 64] = y1;
        }
    }
}

// ---------------------------------------------------------------------------
// MFMA flash attention, bf16 in/out. qkv (TOK,384) bf16; out (TOK,128) bf16.
// grid (SEQL/64, 16). block 256 = 4 waves; wave owns 16 Q rows; K-tile 64.
__global__ __launch_bounds__(256) void attn_mfma(const short* __restrict__ qkv,
                                                 short* __restrict__ out) {
    __shared__ short Ks[64][36];       // K[key][d]
    __shared__ short Vt[32][76];       // V^T[d][key]
    __shared__ short Pb[4][16][76];    // per-wave P[m][n]
    const int bh = blockIdx.y, b = bh >> 2, h = bh & 3;
    const int q0 = blockIdx.x * 64;
    const int tid = threadIdx.x, w = tid >> 6, lane = tid & 63;
    const int la = lane & 15, quad = lane >> 4;
    const size_t tokbase = (size_t)b * SEQL;
    const int hcol = h * 32;
    const float SCL = 0.17677669529663687f;   // 1/sqrt(32)

    // Q fragment (A-layout), prescaled by 1/sqrt(d)
    short8 qa;
    {
        const short* qp = qkv + (tokbase + q0 + w * 16 + la) * 384 + hcol + quad * 8;
        short8 qr = *(const short8*)qp;
        #pragma unroll
        for (int j = 0; j < 8; ++j) qa[j] = f2b(b2f(qr[j]) * SCL);
    }
    float4v o0 = {}, o1 = {};
    float mr[4], lr[4];
    #pragma unroll
    for (int i = 0; i < 4; ++i) { mr[i] = -1e30f; lr[i] = 0.f; }

    const int srow = tid >> 2, sd0 = (tid & 3) * 8;
    for (int kt = 0; kt < SEQL; kt += 64) {
        // stage K tile [64][32]
        {
            const short* kp = qkv + (tokbase + kt + srow) * 384 + 128 + hcol + sd0;
            short8 kr = *(const short8*)kp;
            *(short4v*)&Ks[srow][sd0]     = *(short4v*)&kr;
            *(short4v*)&Ks[srow][sd0 + 4] = *((short4v*)&kr + 1);
        }
        // stage V tile transposed [32 d][64 keys]
        {
            const short* vp = qkv + (tokbase + kt + srow) * 384 + 256 + hcol + sd0;
            short8 vr = *(const short8*)vp;
            #pragma unroll
            for (int j = 0; j < 8; ++j) Vt[sd0 + j][srow] = vr[j];
        }
        __syncthreads();

        // scores: 16 q-rows x 64 keys (4 C-frags)
        float4v sc[4];
        #pragma unroll
        for (int f = 0; f < 4; ++f) {
            short8 kb;
            *(short4v*)&kb       = *(short4v*)&Ks[f * 16 + la][quad * 8];
            *((short4v*)&kb + 1) = *(short4v*)&Ks[f * 16 + la][quad * 8 + 4];
            float4v z = {};
            sc[f] = __builtin_amdgcn_mfma_f32_16x16x32_bf16(qa, kb, z, 0, 0, 0);
        }
        // online softmax per row (row = quad*4+i, spread over 16 la lanes)
        #pragma unroll
        for (int i = 0; i < 4; ++i) {
            float mx = fmaxf(fmaxf(sc[0][i], sc[1][i]), fmaxf(sc[2][i], sc[3][i]));
            mx = fmaxf(mx, __shfl_xor(mx, 1));
            mx = fmaxf(mx, __shfl_xor(mx, 2));
            mx = fmaxf(mx, __shfl_xor(mx, 4));
            mx = fmaxf(mx, __shfl_xor(mx, 8));
            float mn = fmaxf(mr[i], mx);
            float al = __expf(mr[i] - mn);
            mr[i] = mn;
            float rs = 0.f;
            #pragma unroll
            for (int f = 0; f < 4; ++f) {
                float pp = __expf(sc[f][i] - mn);
                sc[f][i] = pp; rs += pp;
            }
            rs += __shfl_xor(rs, 1);
            rs += __shfl_xor(rs, 2);
            rs += __shfl_xor(rs, 4);
            rs += __shfl_xor(rs, 8);
            lr[i] = lr[i] * al + rs;
            o0[i] *= al;
            o1[i] *= al;
            #pragma unroll
            for (int f = 0; f < 4; ++f)
                Pb[w][quad * 4 + i][f * 16 + la] = f2b(sc[f][i]);
        }
        // PV: O[m][d] += P[m][n] V[n][d]
        #pragma unroll
        for (int c = 0; c < 2; ++c) {
            short8 pa;
            *(short4v*)&pa       = *(short4v*)&Pb[w][la][c * 32 + quad * 8];
            *((short4v*)&pa + 1) = *(short4v*)&Pb[w][la][c * 32 + quad * 8 + 4];
            short8 vb0, vb1;
            *(short4v*)&vb0       = *(short4v*)&Vt[la][c * 32 + quad * 8];
            *((short4v*)&vb0 + 1) = *(short4v*)&Vt[la][c * 32 + quad * 8 + 4];
            *(short4v*)&vb1       = *(short4v*)&Vt[16 + la][c * 32 + quad * 8];
            *((short4v*)&vb1 + 1) = *(short4v*)&Vt[16 + la][c * 32 + quad * 8 + 4];
            o0 = __builtin_amdgcn_mfma_f32_16x16x32_bf16(pa, vb0, o0, 0, 0, 0);
            o1 = __builtin_amdgcn_mfma_f32_16x16x32_bf16(pa, vb1, o1, 0, 0, 0);
        }
        __syncthreads();
    }
    #pragma unroll
    for (int i = 0; i < 4; ++i) {
        float li = 1.f / lr[i];
        short* op = out + (tokbase + q0 + w * 16 + quad * 4 + i) * 128 + hcol;
        op[la]      = f2b(o0[i] * li);
        op[16 + la] = f2b(o1[i] * li);
    }
}

// ---------------------------------------------------------------------------
// causal depthwise conv (K=4) + silu. xz (TOK,512) fp32, x cols [0,256).
// outputs fp32 + bf16
__global__ __launch_bounds__(256) void conv_silu_kernel(const float* __restrict__ xz,
                                                        const float* __restrict__ w,
                                                        const float* __restrict__ cb,
                                                        float* __restrict__ out,
                                                        short* __restrict__ outb) {
    int idx = blockIdx.x * 256 + threadIdx.x;
    int d = idx & 255; int t = (idx >> 8) & (SEQL - 1); int b = idx >> 19;
    float acc = cb[d];
    #pragma unroll
    for (int k = 0; k < 4; ++k) {
        int tt = t - 3 + k;
        if (tt >= 0)
            acc += xz[((size_t)b * SEQL + tt) * 512 + d] * w[d * 4 + k];
    }
    float sv = acc / (1.f + __expf(-acc));
    out[idx] = sv;
    outb[idx] = f2b(sv);
}

// ---------------------------------------------------------------------------
// SSM chunked scan.
__global__ __launch_bounds__(256) void scan_a(const float* __restrict__ dt,
                                              const float* __restrict__ xc,
                                              const float* __restrict__ dbc,
                                              const float* __restrict__ A_log,
                                              float* __restrict__ PS) {
    const int c = blockIdx.x & (NCHUNK - 1);
    const int dg = (blockIdx.x >> 5) & 15;
    const int b = blockIdx.x >> 9;
    const int dl = threadIdx.x >> 4, n = threadIdx.x & 15;
    const int d = dg * 16 + dl;
    const float Av = -__expf(A_log[d * 16 + n]);
    float P = 1.f, S = 0.f;
    const size_t tbase = (size_t)b * SEQL + c * TCHUNK;
    for (int t = 0; t < TCHUNK; ++t) {
        float dtv = dt[(tbase + t) * 256 + d];
        float xv = xc[(tbase + t) * 256 + d];
        float Bv = dbc[(tbase + t) * 40 + 8 + n];
        float a = __expf(dtv * Av);
        P *= a;
        S = a * S + dtv * xv * Bv;
    }
    size_t o = (((size_t)b * NCHUNK + c) * 256 + d) * 16 + n;
    PS[o] = S;
    PS[o + (size_t)BATCH * NCHUNK * 256 * 16] = P;
}

__global__ __launch_bounds__(256) void scan_b(const float* __restrict__ PS,
                                              float* __restrict__ H0) {
    int idx = blockIdx.x * 256 + threadIdx.x;   // BATCH*256*16 = 16384
    int n = idx & 15; int d = (idx >> 4) & 255; int b = idx >> 12;
    float h = 0.f;
    const size_t poff = (size_t)BATCH * NCHUNK * 256 * 16;
    for (int c = 0; c < NCHUNK; ++c) {
        size_t o = (((size_t)b * NCHUNK + c) * 256 + d) * 16 + n;
        H0[o] = h;
        h = PS[o + poff] * h + PS[o];
    }
}

__global__ __launch_bounds__(256) void scan_c(const float* __restrict__ dt,
                                              const float* __restrict__ xc,
                                              const float* __restrict__ dbc,
                                              const float* __restrict__ A_log,
                                              const float* __restrict__ H0,
                                              const float* __restrict__ xz,
                                              const float* __restrict__ Dp,
                                              short* __restrict__ yb) {
    const int c = blockIdx.x & (NCHUNK - 1);
    const int dg = (blockIdx.x >> 5) & 15;
    const int b = blockIdx.x >> 9;
    const int dl = threadIdx.x >> 4, n = threadIdx.x & 15;
    const int d = dg * 16 + dl;
    const float Av = -__expf(A_log[d * 16 + n]);
    const float Dv = Dp[d];
    size_t o0 = (((size_t)b * NCHUNK + c) * 256 + d) * 16 + n;
    float h = H0[o0];
    const size_t tbase = (size_t)b * SEQL + c * TCHUNK;
    for (int t = 0; t < TCHUNK; ++t) {
        float dtv = dt[(tbase + t) * 256 + d];
        float xv = xc[(tbase + t) * 256 + d];
        float Bv = dbc[(tbase + t) * 40 + 8 + n];
        float Cv = dbc[(tbase + t) * 40 + 24 + n];
        float a = __expf(dtv * Av);
        h = a * h + dtv * xv * Bv;
        float p = h * Cv;
        p += __shfl_xor(p, 1); p += __shfl_xor(p, 2);
        p += __shfl_xor(p, 4); p += __shfl_xor(p, 8);
        if (n == 0) {
            float zv = xz[(tbase + t) * 512 + 256 + d];
            float sz = zv / (1.f + __expf(-zv));
            yb[(tbase + t) * 256 + d] = f2b((p + xv * Dv) * sz);
        }
    }
}

// ---------------------------------------------------------------------------
static inline void launch_gemm(const short* A, const short* W, const float* bias,
                               const float* res, float* Cf, short* Cb,
                               int M, int N, int K, int lda, int act, hipStream_t s) {
    dim3 g((N + 63) / 64, M / 64);
    hipLaunchKernelGGL(gemm_mfma, g, dim3(256), 0, s, A, W, bias, res, Cf, Cb,
                       M, N, K, lda, act);
}

static const int kSizes[NPAR] = {
    2097152, 32768, 128, 98304, 768, 32768, 256, 131072, 1024, 131072, 256,
    256, 256, 256, 256, 768, 768, 393216, 6144, 1536, 61440, 12288, 1536,
    24576, 1536, 196608, 128, 128
};

extern "C" void kernel_launch(void* const* d_in, const int* in_sizes, int n_in,
                              void* d_out, int out_size, void* d_ws, size_t ws_size,
                              hipStream_t stream) {
    Srcs srcs;
    int off[NPAR + 1];
    off[0] = 0;
    for (int i = 0; i < NPAR; ++i) {
        srcs.p[i] = d_in[i];
        off[i + 1] = off[i] + kSizes[i];
        srcs.off[i] = off[i];
    }
    srcs.off[NPAR] = off[NPAR];

    int* FLAG = (int*)d_ws;
    float* PAR = (float*)((char*)d_ws + 256);
    float* p = PAR + PAR_TOTAL;
    float* H   = p; p += (size_t)TOK * 128;
    float* T1  = p; p += (size_t)TOK * 512;
    float* T2  = p; p += (size_t)TOK * 256;
    float* T3  = p; p += (size_t)TOK * 128;
    float* DBC = p; p += (size_t)TOK * 40;
    float* DT  = p; p += (size_t)TOK * 256;
    float* PS  = p; p += (size_t)2 * BATCH * NCHUNK * 256 * 16;
    float* H0  = p; p += (size_t)BATCH * NCHUNK * 256 * 16;
    // bf16 buffers (each with slack for staging over-read)
    short* q = (short*)p;
    short* PARB = q; q += (size_t)PAR_TOTAL + 128;
    short* Hb   = q; q += (size_t)TOK * 128 + 128;
    short* XNb  = q; q += (size_t)TOK * 128 + 128;
    short* T1B  = q; q += (size_t)TOK * 512 + 128;
    short* OB   = q; q += (size_t)TOK * 128 + 128;
    short* XCb  = q; q += (size_t)TOK * 256 + 128;
    short* DBCb = q; q += (size_t)TOK * 40 + 128;
    short* Yb   = q; q += (size_t)TOK * 256 + 128;

    hipLaunchKernelGGL(sniff_kernel, dim3(1), dim3(128), 0, stream,
                       (const unsigned int*)d_in[0], FLAG);
    hipLaunchKernelGGL(cvt_all, dim3((PAR_TOTAL + 255) / 256), dim3(256), 0, stream,
                       srcs, FLAG, PAR, PARB, PAR_TOTAL);

    const float* Pproj_b   = PAR + off[2];
    const float* Pt_in_b   = PAR + off[4];
    const float* Pt_out_b  = PAR + off[6];
    const float* Pt_ff1_b  = PAR + off[8];
    const float* Pt_ff2_b  = PAR + off[10];
    const float* Pt_n1_s   = PAR + off[11];
    const float* Pt_n1_b   = PAR + off[12];
    const float* Pt_n2_s   = PAR + off[13];
    const float* Pt_n2_b   = PAR + off[14];
    const float* Pm_norm_s = PAR + off[15];
    const float* Pm_norm_b = PAR + off[16];
    const float* Pm_conv_w = PAR + off[18];
    const float* Pm_conv_b = PAR + off[19];
    const float* Pm_dt_b   = PAR + off[22];
    const float* Pm_A_log  = PAR + off[23];
    const float* Pm_D      = PAR + off[24];
    const float* Pnorm_s   = PAR + off[26];
    const float* Pnorm_b   = PAR + off[27];

    const short* BxB       = PARB + off[0];
    const short* Bproj_w   = PARB + off[1];
    const short* Bt_in_w   = PARB + off[3];
    const short* Bt_out_w  = PARB + off[5];
    const short* Bt_ff1_w  = PARB + off[7];
    const short* Bt_ff2_w  = PARB + off[9];
    const short* Bm_in_w   = PARB + off[17];
    const short* Bm_xproj_w= PARB + off[20];
    const short* Bm_dt_w   = PARB + off[21];
    const short* Bm_out_w  = PARB + off[25];

    // input proj: H = x @ proj_w.T + proj_b  (writes fp32 + bf16)
    launch_gemm(BxB, Bproj_w, Pproj_b, nullptr, H, Hb, TOK, 128, 256, 256, 0, stream);

    const char sched[9] = "TMMMTMMM";
    int ti = 0, mi = 0;
    for (int li = 0; li < 8; ++li) {
        if (sched[li] == 'T') {
            launch_gemm(Hb, Bt_in_w + (size_t)ti * 384 * 128, Pt_in_b + ti * 384,
                        nullptr, nullptr, T1B, TOK, 384, 128, 128, 0, stream);
            hipLaunchKernelGGL(attn_mfma, dim3(SEQL / 64, 16), dim3(256), 0, stream,
                               T1B, OB);
            launch_gemm(OB, Bt_out_w + (size_t)ti * 128 * 128, Pt_out_b + ti * 128,
                        H, T3, nullptr, TOK, 128, 128, 128, 0, stream);
            hipLaunchKernelGGL(ln_kernel, dim3(TOK / 4), dim3(256), 0, stream,
                               T3, Pt_n1_s + ti * 128, Pt_n1_b + ti * 128,
                               H, Hb, (void*)nullptr, FLAG);
            launch_gemm(Hb, Bt_ff1_w + (size_t)ti * 512 * 128, Pt_ff1_b + ti * 512,
                        nullptr, nullptr, T1B, TOK, 512, 128, 128, 1, stream);
            launch_gemm(T1B, Bt_ff2_w + (size_t)ti * 128 * 512, Pt_ff2_b + ti * 128,
                        H, T3, nullptr, TOK, 128, 512, 512, 0, stream);
            hipLaunchKernelGGL(ln_kernel, dim3(TOK / 4), dim3(256), 0, stream,
                               T3, Pt_n2_s + ti * 128, Pt_n2_b + ti * 128,
                               H, Hb, (void*)nullptr, FLAG);
            ++ti;
        } else {
            hipLaunchKernelGGL(ln_kernel, dim3(TOK / 4), dim3(256), 0, stream,
                               H, Pm_norm_s + mi * 128, Pm_norm_b + mi * 128,
                               (float*)nullptr, XNb, (void*)nullptr, FLAG);
            launch_gemm(XNb, Bm_in_w + (size_t)mi * 512 * 128, nullptr, nullptr,
                        T1, nullptr, TOK, 512, 128, 128, 0, stream);
            hipLaunchKernelGGL(conv_silu_kernel, dim3(TOK), dim3(256), 0, stream,
                               T1, Pm_conv_w + mi * 256 * 4, Pm_conv_b + mi * 256,
                               T2, XCb);
            launch_gemm(XCb, Bm_xproj_w + (size_t)mi * 40 * 256, nullptr, nullptr,
                        DBC, DBCb, TOK, 40, 256, 256, 0, stream);
            launch_gemm(DBCb, Bm_dt_w + (size_t)mi * 256 * 8, Pm_dt_b + mi * 256,
                        nullptr, DT, nullptr, TOK, 256, 8, 40, 2, stream);
            hipLaunchKernelGGL(scan_a, dim3(BATCH * 16 * NCHUNK), dim3(256), 0, stream,
                               DT, T2, DBC, Pm_A_log + (size_t)mi * 256 * 16, PS);
            hipLaunchKernelGGL(scan_b, dim3(64), dim3(256), 0, stream, PS, H0);
            hipLaunchKernelGGL(scan_c, dim3(BATCH * 16 * NCHUNK), dim3(256), 0, stream,
                               DT, T2, DBC, Pm_A_log + (size_t)mi * 256 * 16, H0, T1,
                               Pm_D + mi * 256, Yb);
            launch_gemm(Yb, Bm_out_w + (size_t)mi * 128 * 256, nullptr, H, H, Hb,
                        TOK, 128, 256, 256, 0, stream);
            ++mi;
        }
    }
    hipLaunchKernelGGL(ln_kernel, dim3(TOK / 4), dim3(256), 0, stream,
                       H, Pnorm_s, Pnorm_b, (float*)nullptr, (short*)nullptr,
                       d_out, FLAG);
}